// Round 9
// baseline (3853.624 us; speedup 1.0000x reference)
//
#include <hip/hip_runtime.h>
#include <hip/hip_bf16.h>

#define H     768
#define G3    2304
#define BATCH 16
#define TLEN  1024
#define DOUT  512
#define SLICE 32
#define WPG   24      // workgroups per scan group (768/32)
#define NSCAN 96      // 4 scan groups * 24
#define NFC   64      // fused fc workgroups
#define NWG   160     // 96 scan + 64 fc
#define NTHR  384     // 6 waves

typedef __attribute__((ext_vector_type(8))) short short8;
typedef __attribute__((ext_vector_type(4))) float f32x4;
typedef __attribute__((ext_vector_type(4))) unsigned int u32x4;

union U8 { short8 s; unsigned u[4]; unsigned long long q[2]; };

__device__ __forceinline__ float b2f(ushort u) {
  union { unsigned int ui; float f; } v; v.ui = ((unsigned int)u) << 16; return v.f;
}
__device__ __forceinline__ ushort f2b(float f) {
  union { float f; unsigned int ui; } v; v.f = f;
  unsigned int u = v.ui;
  return (ushort)((u + 0x7fffu + ((u >> 16) & 1u)) >> 16);
}

// ---- agent-scope (cross-XCD coherent) relaxed accessors ----
__device__ __forceinline__ unsigned long long agent_ld64(const void* p) {
  return __hip_atomic_load((const unsigned long long*)p, __ATOMIC_RELAXED, __HIP_MEMORY_SCOPE_AGENT);
}
__device__ __forceinline__ unsigned agent_ld32(const void* p) {
  return __hip_atomic_load((const unsigned*)p, __ATOMIC_RELAXED, __HIP_MEMORY_SCOPE_AGENT);
}
__device__ __forceinline__ void agent_st32(void* p, unsigned v) {
  __hip_atomic_store((unsigned*)p, v, __ATOMIC_RELAXED, __HIP_MEMORY_SCOPE_AGENT);
}
__device__ __forceinline__ void agent_st64(void* p, unsigned long long v) {
  __hip_atomic_store((unsigned long long*)p, v, __ATOMIC_RELAXED, __HIP_MEMORY_SCOPE_AGENT);
}

// 64B coherent (agent-scope, cache-bypassing) load: 4 x dwordx4 with sc0 sc1.
__device__ __forceinline__ void ld64B_agent(const void* p, u32x4* r) {
  asm volatile(
    "global_load_dwordx4 %0, %4, off sc0 sc1\n\t"
    "global_load_dwordx4 %1, %4, off offset:16 sc0 sc1\n\t"
    "global_load_dwordx4 %2, %4, off offset:32 sc0 sc1\n\t"
    "global_load_dwordx4 %3, %4, off offset:48 sc0 sc1\n\t"
    "s_waitcnt vmcnt(0)"
    : "=&v"(r[0]), "=&v"(r[1]), "=&v"(r[2]), "=&v"(r[3])
    : "v"(p) : "memory");
}

// 4 x 16B coherent loads from 4 independent addresses, single vmcnt drain.
__device__ __forceinline__ void ld4x16B_agent(const void* p0, const void* p1,
                                              const void* p2, const void* p3,
                                              u32x4* r) {
  asm volatile(
    "global_load_dwordx4 %0, %4, off sc0 sc1\n\t"
    "global_load_dwordx4 %1, %5, off sc0 sc1\n\t"
    "global_load_dwordx4 %2, %6, off sc0 sc1\n\t"
    "global_load_dwordx4 %3, %7, off sc0 sc1\n\t"
    "s_waitcnt vmcnt(0)"
    : "=&v"(r[0]), "=&v"(r[1]), "=&v"(r[2]), "=&v"(r[3])
    : "v"(p0), "v"(p1), "v"(p2), "v"(p3) : "memory");
}

// 16-byte-granular load of 8 elements as bf16 fragment (plain/cached path).
__device__ __forceinline__ short8 loadA8(const void* base, bool bf, size_t eidx) {
  if (bf) return *(const short8*)((const ushort*)base + eidx);
  const uint4* f = (const uint4*)((const float*)base + eidx);
  uint4 lo = f[0];
  uint4 hi = f[1];
  U8 r;
  r.u[0] = __builtin_amdgcn_perm(lo.y, lo.x, 0x07060302);
  r.u[1] = __builtin_amdgcn_perm(lo.w, lo.z, 0x07060302);
  r.u[2] = __builtin_amdgcn_perm(hi.y, hi.x, 0x07060302);
  r.u[3] = __builtin_amdgcn_perm(hi.w, hi.z, 0x07060302);
  return r.s;
}
__device__ __forceinline__ short8 loadW8(const void* base, bool bf, size_t eidx) {
  if (bf) return *(const short8*)((const ushort*)base + eidx);
  const float* f = (const float*)base + eidx;
  short8 r;
  #pragma unroll
  for (int i = 0; i < 8; i++) r[i] = (short)f2b(f[i]);
  return r;
}
__device__ __forceinline__ float loadS(const void* p, bool bf, size_t i) {
  return bf ? b2f(((const ushort*)p)[i]) : ((const float*)p)[i];
}

__device__ __forceinline__ bool detect_bf16(const unsigned* xw, int tid, int nthr, int* sh) {
  if (tid == 0) *sh = 0;
  __syncthreads();
  int c = 0;
  for (int i = tid; i < 4096; i += nthr) {
    int e = (int)((xw[i] >> 7) & 0xFF);
    c += (e >= 110 && e <= 140) ? 1 : 0;
  }
  atomicAdd(sh, c);
  __syncthreads();
  return *sh > 2048;
}

// flag line: flags[((grp*WPG + wgi)*4 + rep)*32], 128B apart
__device__ __forceinline__ unsigned* flagp(unsigned* flags, int grp, int wgi, int rep) {
  return flags + (((grp * WPG + wgi) * 4 + rep) * 32);
}

// ---------------------------------------------------------------------------
// Persistent pipelined GRU scan + fused FC.  R8 protocol (verified), with
// DECENTRALIZED PER-WAVE SLICE STAGING replacing the bulk gate:
//   - MFMA chunk kk consumes exactly producer WG kk's 32 columns.  Wave w
//     owns slices {w, w+6, w+12, w+18}: polls those 4 producer flags itself
//     (1 poller/line/consumer-WG, same totals as R4), issues the 4 coherent
//     16B/lane loads in ONE asm block (1 LLC RT), ds_writes to slice-major
//     LDS (2 lanes/bank - conflict-free), publishes LDS token wready[w]
//     (release).  MFMA waves gate on the 6 tokens (acquire) - no barriers
//     between flag arrival and MFMA; early slices overlap stragglers.
//   - Slack/aux edges (gx-ready, slot-reuse; normally pre-satisfied) are
//     polled by wave0 -> LDS token slackok gating gx loads and stores.
// Scan groups: 0=GX1 (w_ih1 @ x), 1=L1 (-> h1), 2=GX2 (w_ih2 @ h1),
//              3=GH2 (-> y2=h2 history).  lag={0,1,2,4}; 4-deep slots.
// Flag value = ticks completed.  Staging flags (>= t): L1: F_L1 r0[kk];
// GX2: F_L1 r1[kk]; GH2: F_GH2 r0[kk].  Slack (wave0): GX1: F_L1 r2[wgi]-2;
// L1: F_GX1 r0[wgi] 0 + F_GX2 r0[all] -2; GX2: F_GH2 r1[wgi] -1;
// GH2: F_GX2 r1[wgi] -1.
// FC group (wg 96..159): WG fcw owns t = fcw + 64*i; waits GH2 flags >=
// t+5 (replicas r2/r3), stages y2[:,t,:], MFMA vs w_fc, bias+GELU -> out.
// ---------------------------------------------------------------------------
__global__ __launch_bounds__(NTHR) void scan_kernel(
    const void* __restrict__ x,        // [16][1024][768]
    const void* __restrict__ w_ih,     // [2][2304][768]
    const void* __restrict__ w_hh,     // [2][2304][768]
    const void* __restrict__ b_ih,     // [2][2304]
    const void* __restrict__ b_hh,     // [2][2304]
    const void* __restrict__ w_fc,     // [512][768]
    const void* __restrict__ b_fc,     // [512]
    unsigned int* flags,               // [4][24][4][32] padded flags (zeroed)
    ushort* h1buf,                     // [4][16][768] bf16
    float*  gxbuf1,                    // [4][24][16][96] f32 (per-WG slices)
    float*  gxbuf2,                    // [4][24][16][96] f32
    ushort* y2,                        // [16][1024][768] bf16 (= h2 history)
    void* __restrict__ out)            // [16][1024][512] bf16 or f32
{
  const int wg   = blockIdx.x;
  const int tid  = threadIdx.x;
  const int wave = tid >> 6;           // 0..5
  const int lane = tid & 63;
  const int quad = lane >> 4;          // 0..3
  const int ar   = lane & 15;          // batch row for staging & MFMA A

  __shared__ ushort lA[24 * 512];          // A slices [kk][row16][col8x4], 24 KB
  __shared__ float ghs[96 * 17];           // MFMA C tile [gate-col][batch]
  __shared__ float hold[BATCH * SLICE];    // persistent fp32 h slice
  __shared__ float bih_s[96], bhh_s[96];
  __shared__ int wready[6];                // per-wave staging tokens
  __shared__ int slackok;                  // slack-edges token
  __shared__ int detsh;

  const bool isbf = detect_bf16((const unsigned*)x, tid, NTHR, &detsh);

  // =========================== FC group ===================================
  if (wg >= NSCAN) {
    const int fcw = wg - NSCAN;        // 0..63
    const unsigned* fpoll = (wave == 0 && lane < WPG)
        ? flagp(flags, 3, lane, (fcw < 32) ? 2 : 3) : nullptr;
    const int sb  = tid / 24;          // 0..15 (batch row)
    const int seg = tid % 24;          // 0..23 (32-elem segment)
    const int sx  = sb & 7;
    const int arx = ar & 7;

    for (int i = 0; i < 16; i++) {
      const int t = fcw + 64 * i;
      // ---- wait: all GH2 WGs completed tick t+4 (=> y2[t] stored+acked) --
      if (wave == 0) {
        const int tgt = t + 5;
        for (;;) {
          int v = fpoll ? (int)agent_ld32(fpoll) : 0x7FFFFFFF;
          if (__ballot(v < tgt) == 0ull) break;
          __builtin_amdgcn_s_sleep(8);
        }
      }
      __syncthreads();

      // ---- stage y2[:, t, :] (16 x 768 bf16) into LDS, swizzled ---------
      {
        const ushort* src = y2 + ((size_t)sb * TLEN + t) * H + seg * 32;
        u32x4 r4[4];
        ld64B_agent(src, r4);
        #pragma unroll
        for (int j = 0; j < 4; j++)
          *(u32x4*)&lA[sb * H + (((seg * 4 + j) ^ sx) * 8)] = r4[j];
      }
      __syncthreads();

      // ---- MFMA: out[:, t, n0..n0+128) per wave (waves 0..3) ------------
      if (wave < 4) {
        const int n0 = wave * 128;
        const ushort* abase = &lA[ar * H];
        f32x4 acc[8];
        #pragma unroll
        for (int nt = 0; nt < 8; nt++) acc[nt] = (f32x4){0.f, 0.f, 0.f, 0.f};
        for (int kk = 0; kk < 12; kk++) {
          short8 a0 = *(const short8*)&abase[((quad + 4 * kk) ^ arx) * 8];
          short8 a1 = *(const short8*)&abase[((quad + 4 * (kk + 12)) ^ arx) * 8];
          #pragma unroll
          for (int nt = 0; nt < 8; nt++) {
            const size_t bb = (size_t)(n0 + nt * 16 + ar) * H + quad * 8;
            short8 b0 = loadA8(w_fc, isbf, bb + kk * 32);
            short8 b1 = loadA8(w_fc, isbf, bb + (kk + 12) * 32);
            acc[nt] = __builtin_amdgcn_mfma_f32_16x16x32_bf16(a0, b0, acc[nt], 0, 0, 0);
            acc[nt] = __builtin_amdgcn_mfma_f32_16x16x32_bf16(a1, b1, acc[nt], 0, 0, 0);
          }
        }
        #pragma unroll
        for (int nt = 0; nt < 8; nt++) {
          #pragma unroll
          for (int i2 = 0; i2 < 4; i2++) {
            const int b = quad * 4 + i2;
            const int n = n0 + nt * 16 + ar;
            float v = acc[nt][i2] + loadS(b_fc, isbf, n);
            float g = 0.5f * v * (1.0f + erff(v * 0.70710678118654752f));
            if (isbf) ((ushort*)out)[((size_t)b * TLEN + t) * DOUT + n] = f2b(g);
            else      ((float*)out)[((size_t)b * TLEN + t) * DOUT + n] = g;
          }
        }
      }
      __syncthreads();                 // LDS reuse guard before next t
    }
    return;
  }

  // =========================== scan groups ================================
  const int grp  = wg / WPG;           // 0..3
  const int wgi  = wg % WPG;           // 0..23 -> gate columns [wgi*32, +32)
  const bool isL = (grp == 1 || grp == 3);

  for (int i = tid; i < BATCH * SLICE; i += NTHR) hold[i] = 0.0f;
  if (tid == 0) slackok = -1;
  if (tid < 6) wready[tid] = -1;

  if (isL) {
    size_t boff = (grp == 3) ? (size_t)G3 : 0;
    for (int gf = tid; gf < 96; gf += NTHR) {
      size_t gidx = boff + (size_t)(gf >> 5) * H + wgi * SLICE + (gf & 31);
      bih_s[gf] = loadS(b_ih, isbf, gidx);
      bhh_s[gf] = loadS(b_hh, isbf, gidx);
    }
  }

  // ---- wave0 slack-edge poll pointers (store/gx gating, normally slack) --
  const unsigned* pollp = nullptr;
  int polloff = 0;
  if (wave == 0) {
    if (grp == 0) {
      if (lane == 0) { pollp = flagp(flags, 1, wgi, 2); polloff = -2; }
    } else if (grp == 1) {
      if      (lane == 0)  { pollp = flagp(flags, 0, wgi, 0);       polloff = 0;  }
      else if (lane <= 24) { pollp = flagp(flags, 2, lane - 1, 0);  polloff = -2; }
    } else if (grp == 2) {
      if (lane == 0) { pollp = flagp(flags, 3, wgi, 1); polloff = -1; }
    } else {
      if (lane == 0) { pollp = flagp(flags, 2, wgi, 1); polloff = -1; }
    }
  }

  // ---- per-wave staging flag line (lanes 0..3 poll slices wave+6*lane) ---
  const unsigned* sfl = nullptr;
  if (grp != 0 && lane < 4) {
    const int fg = (grp == 3) ? 3 : 1;
    const int fr = (grp == 2) ? 1 : 0;
    sfl = flagp(flags, fg, wave + 6 * lane, fr);
  }

  // ---- load this wave's B-fragments (16 gate rows x K=768) into registers --
  const void* Wmat = (grp == 0 || grp == 2) ? w_ih : w_hh;
  const size_t woff = (grp >= 2) ? (size_t)G3 * H : 0;
  const int gate   = wave >> 1;                       // 0=r,1=z,2=n
  const int gfbase = gate * SLICE + (wave & 1) * 16;  // within-wg flat gate base
  const int nrow   = gate * H + wgi * SLICE + (wave & 1) * 16 + ar;
  const size_t wbase = woff + (size_t)nrow * H + quad * 8;

  short8 bfrag[24];
  #pragma unroll
  for (int kk = 0; kk < 24; kk++)
    bfrag[kk] = loadW8(Wmat, isbf, wbase + kk * 32);

  // combine decomposition: 256 threads, pairs of columns
  const int pb = tid >> 4;             // batch
  const int pj = (tid & 15) * 2;       // column pair
  const bool pact = isL && (tid < BATCH * SLICE / 2);

  const int lag = (grp == 1) ? 1 : ((grp == 2) ? 2 : ((grp == 3) ? 4 : 0));

  __syncthreads();

  for (int t = 0; t < TLEN + 4; t++) {
    const int tau = t - lag;
    const bool active = (tau >= 0) && (tau < TLEN);

    if (active) {
      // ---- per-wave slice staging (no barriers) ----
      if (grp == 0) {
        #pragma unroll
        for (int s = 0; s < 4; s++) {
          const int kk = wave + 6 * s;
          short8 v = loadA8(x, isbf,
              ((size_t)ar * TLEN + tau) * H + kk * 32 + quad * 8);
          *(short8*)&lA[kk * 512 + ar * 32 + quad * 8] = v;
        }
      } else {
        const int hstep = (grp == 3) ? (t - 5) : (t - 2);
        if (hstep >= 0) {
          // poll this wave's 4 producer flags (>= t)
          for (;;) {
            int v = sfl ? (int)agent_ld32(sfl) : 0x7FFFFFFF;
            if (__ballot(v < t) == 0ull) break;
            __builtin_amdgcn_s_sleep(1);
          }
          const ushort* srcb = (grp == 3)
              ? y2 + ((size_t)ar * TLEN + hstep) * H + quad * 8
              : h1buf + (size_t)(hstep & 3) * (BATCH * H) + (size_t)ar * H + quad * 8;
          u32x4 r4[4];
          ld4x16B_agent(srcb + (wave +  0) * 32, srcb + (wave +  6) * 32,
                        srcb + (wave + 12) * 32, srcb + (wave + 18) * 32, r4);
          *(u32x4*)&lA[(wave +  0) * 512 + ar * 32 + quad * 8] = r4[0];
          *(u32x4*)&lA[(wave +  6) * 512 + ar * 32 + quad * 8] = r4[1];
          *(u32x4*)&lA[(wave + 12) * 512 + ar * 32 + quad * 8] = r4[2];
          *(u32x4*)&lA[(wave + 18) * 512 + ar * 32 + quad * 8] = r4[3];
        } else {
          u32x4 z = (u32x4){0u, 0u, 0u, 0u};
          #pragma unroll
          for (int s = 0; s < 4; s++)
            *(u32x4*)&lA[(wave + 6 * s) * 512 + ar * 32 + quad * 8] = z;
        }
      }
      if (lane == 0)
        __hip_atomic_store(&wready[wave], t, __ATOMIC_RELEASE,
                           __HIP_MEMORY_SCOPE_WORKGROUP);

      // ---- slack edges: wave0 polls -> slackok; others spin ----
      if (wave == 0) {
        for (;;) {
          int v = pollp ? (int)agent_ld32(pollp) : 0x7FFFFFFF;
          if (__ballot(v < t + polloff) == 0ull) break;
          __builtin_amdgcn_s_sleep(1);
        }
        if (lane == 0)
          __hip_atomic_store(&slackok, t, __ATOMIC_RELEASE,
                             __HIP_MEMORY_SCOPE_WORKGROUP);
      } else {
        while (__hip_atomic_load(&slackok, __ATOMIC_ACQUIRE,
                                 __HIP_MEMORY_SCOPE_WORKGROUP) < t)
          __builtin_amdgcn_s_sleep(1);
      }

      // ---- early-issue combine-phase gx loads (in flight through MFMA) ---
      unsigned long long gr01 = 0, gz01 = 0, gn01 = 0;
      if (pact) {
        const float* gxr = ((grp == 1) ? gxbuf1 : gxbuf2)
            + ((size_t)((tau & 3) * WPG + wgi) * BATCH + pb) * 96;
        gr01 = agent_ld64(gxr + pj);
        gz01 = agent_ld64(gxr + 32 + pj);
        gn01 = agent_ld64(gxr + 64 + pj);
      }

      // ---- gate on all 6 staging tokens, then MFMA ----
      for (;;) {
        bool ok = true;
        #pragma unroll
        for (int w2 = 0; w2 < 6; w2++)
          ok &= (__hip_atomic_load(&wready[w2], __ATOMIC_ACQUIRE,
                                   __HIP_MEMORY_SCOPE_WORKGROUP) >= t);
        if (ok) break;
      }

      f32x4 acc0 = {0.f, 0.f, 0.f, 0.f}, acc1 = {0.f, 0.f, 0.f, 0.f};
      #pragma unroll
      for (int kk = 0; kk < 12; kk++) {
        short8 a0 = *(const short8*)&lA[kk * 512 + ar * 32 + quad * 8];
        short8 a1 = *(const short8*)&lA[(kk + 12) * 512 + ar * 32 + quad * 8];
        acc0 = __builtin_amdgcn_mfma_f32_16x16x32_bf16(a0, bfrag[kk],      acc0, 0, 0, 0);
        acc1 = __builtin_amdgcn_mfma_f32_16x16x32_bf16(a1, bfrag[kk + 12], acc1, 0, 0, 0);
      }
      f32x4 acc = acc0 + acc1;

      // ---- stage C tile to LDS ----
      #pragma unroll
      for (int i = 0; i < 4; i++)
        ghs[(gfbase + ar) * 17 + quad * 4 + i] = acc[i];
      __syncthreads();

      if (!isL) {
        // pack gx slice [16][96] f32 -> coalesced 8B agent stores
        float* gxout = ((grp == 0) ? gxbuf1 : gxbuf2)
            + ((size_t)(tau & 3) * WPG + wgi) * BATCH * 96;
        const int m  = tid / 24;
        const int c4 = (tid % 24) * 4;
        union { unsigned long long q; float f[2]; } p0, p1;
        p0.f[0] = ghs[(c4 + 0) * 17 + m];
        p0.f[1] = ghs[(c4 + 1) * 17 + m];
        p1.f[0] = ghs[(c4 + 2) * 17 + m];
        p1.f[1] = ghs[(c4 + 3) * 17 + m];
        agent_st64(gxout + (size_t)m * 96 + c4,     p0.q);
        agent_st64(gxout + (size_t)m * 96 + c4 + 2, p1.q);
      } else if (pact) {
        union { unsigned long long q; float f[2]; } ur, uz, un;
        ur.q = gr01; uz.q = gz01; un.q = gn01;
        unsigned hpack = 0;
        #pragma unroll
        for (int s = 0; s < 2; s++) {
          const int j = pj + s;
          float rpre = ur.f[s] + bih_s[j]      + ghs[j * 17 + pb]        + bhh_s[j];
          float zpre = uz.f[s] + bih_s[32 + j] + ghs[(32 + j) * 17 + pb] + bhh_s[32 + j];
          float hn   = ghs[(64 + j) * 17 + pb] + bhh_s[64 + j];
          float r = 1.0f / (1.0f + expf(-rpre));
          float z = 1.0f / (1.0f + expf(-zpre));
          float n = tanhf(un.f[s] + bih_s[64 + j] + r * hn);
          float hnew = (1.0f - z) * n + z * hold[pb * SLICE + j];
          hold[pb * SLICE + j] = hnew;
          hpack |= ((unsigned)f2b(hnew)) << (16 * s);
        }
        if (grp == 1)
          agent_st32(h1buf + (size_t)(tau & 3) * (BATCH * H)
                           + (size_t)pb * H + wgi * SLICE + pj, hpack);
        else
          agent_st32(&y2[((size_t)pb * TLEN + tau) * H + wgi * SLICE + pj], hpack);
      }
    }

    // ---- post completion flag (after vmcnt drain) ----
    __syncthreads();                       // drains vmcnt: comms stores visible
    if (tid < 4) agent_st32(flagp(flags, grp, wgi, tid), (unsigned)(t + 1));
  }
}

extern "C" void kernel_launch(void* const* d_in, const int* in_sizes, int n_in,
                              void* d_out, int out_size, void* d_ws, size_t ws_size,
                              hipStream_t stream) {
  const void* x    = d_in[0];
  const void* w_ih = d_in[1];
  const void* w_hh = d_in[2];
  const void* b_ih = d_in[3];
  const void* b_hh = d_in[4];
  const void* w_fc = d_in[5];
  const void* b_fc = d_in[6];

  char* ws = (char*)d_ws;
  // layout: [0,49152) flags[4][24][4][32] |
  //         [53248,151552) h1 (4-deep) | [151552,741376) gx1 (4-deep) |
  //         [741376,1331200) gx2 (4-deep) | [1331200,26497024) y2 (=h2 history)
  unsigned int* flags = (unsigned int*)(ws);
  ushort* h1buf  = (ushort*)(ws + 53248);
  float*  gxbuf1 = (float*)(ws + 151552);
  float*  gxbuf2 = (float*)(ws + 741376);
  ushort* y2     = (ushort*)(ws + 1331200);

  hipMemsetAsync(ws, 0, 49152, stream);  // flags only (data is flag-gated)
  scan_kernel<<<dim3(NWG), dim3(NTHR), 0, stream>>>(
      x, w_ih, w_hh, b_ih, b_hh, w_fc, b_fc, flags,
      h1buf, gxbuf1, gxbuf2, y2, d_out);
}